// Round 25
// baseline (114.959 us; speedup 1.0000x reference)
//
#include <hip/hip_runtime.h>
#include <math.h>

#define NCOL 64
#define M_ROWS 262144

typedef short bf16x8 __attribute__((ext_vector_type(8)));
typedef float f32x4 __attribute__((ext_vector_type(4)));
typedef unsigned int u32x4 __attribute__((ext_vector_type(4)));

// compact upper-triangle S storage: tile-row g keeps cols >= 16g.
__device__ __constant__ const int OFF_G[8] = {0, 512, 960, 1344, 1664, 1920, 2112, 2240};
#define S_COMPACT_F4 2304

__device__ __forceinline__ unsigned short f2bf(float f) {  // RNE fp32->bf16
    unsigned int u = __float_as_uint(f);
    u += 0x7FFFu + ((u >> 16) & 1u);
    return (unsigned short)(u >> 16);
}
__device__ __forceinline__ float bf2f(unsigned short s) {
    return __uint_as_float(((unsigned int)s) << 16);
}
__device__ __forceinline__ unsigned int bfrnd(float f) {
    unsigned int u = __float_as_uint(f);
    return u + 0x7FFFu + ((u >> 16) & 1u);
}
__device__ __forceinline__ unsigned int perm_hi16(unsigned int lo, unsigned int hi) {
    return __builtin_amdgcn_perm(hi, lo, 0x07060302u);
}
__device__ __forceinline__ bf16x8 as_bf16x8(u32x4 v) { return __builtin_bit_cast(bf16x8, v); }

// ---------------- S = Y^T Y via MFMA (1024 blocks, 4/CU); also emits Xh = bf16(X) ----------------
#define GR_BLOCKS 1024
#define GR_KTILES (M_ROWS / 32 / GR_BLOCKS)  // 8

__device__ __forceinline__ void stage_gram(const float4* __restrict__ src4,
                                           float4* lds0, int t) {
#pragma unroll
    for (int i = 0; i < 4; ++i) {
        const int f = t + 256 * i;
        const int sf = f ^ (((f >> 8) & 1) << 2);
        const int base = __builtin_amdgcn_readfirstlane(f & ~63);
        __builtin_amdgcn_global_load_lds(
            (const __attribute__((address_space(1))) unsigned int*)(src4 + sf),
            (__attribute__((address_space(3))) unsigned int*)(lds0 + base), 16, 0, 0);
    }
}

__global__ __launch_bounds__(256) void gram_mfma(const float* __restrict__ X,
                                                 float* __restrict__ Sbufs,
                                                 u32x4* __restrict__ XhOut) {
    __shared__ float4 buf[3][1024];                  // 3 x 16 KB
    const int t = threadIdx.x;
    const int w = t >> 6, l = t & 63, r = l & 15, c = l >> 4;

    f32x4 acc[2][8];
#pragma unroll
    for (int jr = 0; jr < 2; ++jr)
#pragma unroll
        for (int kt = 0; kt < 8; ++kt) acc[jr][kt] = (f32x4){0.f, 0.f, 0.f, 0.f};

    const float4* Xt4 = reinterpret_cast<const float4*>(X) + (size_t)blockIdx.x * 256 * 32;
    const int rb = c * 4096 + r * 4;
    const int cx = (c & 1);

    stage_gram(Xt4, &buf[0][0], t);                  // prologue: tiles 0,1
    stage_gram(Xt4 + 1024, &buf[1][0], t);

    for (int tt = 0; tt < GR_KTILES; ++tt) {
        if (tt + 2 < GR_KTILES)
            stage_gram(Xt4 + (size_t)(tt + 2) * 1024, &buf[(tt + 2) % 3][0], t);
        // queue accounting (4 stage + 2 xh stores per tile):
        if (tt == 0)                     { asm volatile("s_waitcnt vmcnt(8)" ::: "memory"); }
        else if (tt == 1)                { asm volatile("s_waitcnt vmcnt(10)" ::: "memory"); }
        else if (tt == GR_KTILES - 2)    { asm volatile("s_waitcnt vmcnt(8)" ::: "memory"); }
        else if (tt == GR_KTILES - 1)    { asm volatile("s_waitcnt vmcnt(4)" ::: "memory"); }
        else                             { asm volatile("s_waitcnt vmcnt(12)" ::: "memory"); }
        __builtin_amdgcn_sched_barrier(0);
        __builtin_amdgcn_s_barrier();
        __builtin_amdgcn_sched_barrier(0);

        const char* bb = (const char*)&buf[tt % 3][0];

        // linear bf16 convert + store (coalesced); bit-identical to apply's old in-situ convert
        {
            u32x4 xo[2];
#pragma unroll
            for (int i = 0; i < 2; ++i) {
                const int s = t + 256 * i;
                const int row = s >> 4, wv = s & 15;
                const int g0 = row * 32 + wv * 2;
                const int g1 = g0 + 1;
                const int l0 = g0 ^ (((g0 >> 8) & 1) << 2);
                const int l1 = g1 ^ (((g1 >> 8) & 1) << 2);
                const float4 a = *reinterpret_cast<const float4*>(bb + l0 * 16);
                const float4 b2 = *reinterpret_cast<const float4*>(bb + l1 * 16);
                u32x4 o;
                o[0] = perm_hi16(bfrnd(a.x), bfrnd(a.y));
                o[1] = perm_hi16(bfrnd(a.z), bfrnd(a.w));
                o[2] = perm_hi16(bfrnd(b2.x), bfrnd(b2.y));
                o[3] = perm_hi16(bfrnd(b2.z), bfrnd(b2.w));
                xo[i] = o;
            }
            u32x4* Xh4 = XhOut + (size_t)blockIdx.x * (GR_KTILES * 512) + (size_t)tt * 512;
            Xh4[t] = xo[0];
            Xh4[t + 256] = xo[1];
        }

        bf16x8 frag[8];
#pragma unroll
        for (int kt = 0; kt < 8; ++kt) {
            const int cb = (kt ^ cx) * 64;
            float x[8];
#pragma unroll
            for (int i = 0; i < 8; ++i)
                x[i] = *(const float*)(bb + rb + i * 512 + cb);
            u32x4 pw;
#pragma unroll
            for (int wd = 0; wd < 4; ++wd)
                pw[wd] = perm_hi16(bfrnd(x[2 * wd]), bfrnd(x[2 * wd + 1]));
            frag[kt] = as_bf16x8(pw);
        }
#pragma unroll
        for (int s = 0; s < 8; ++s) {
            if ((s >> 1) == w) {
#pragma unroll
                for (int kt = 0; kt < 8; ++kt)
                    acc[s & 1][kt] = __builtin_amdgcn_mfma_f32_16x16x32_bf16(
                        frag[s], frag[kt], acc[s & 1][kt], 0, 0, 0);
            }
        }
        __builtin_amdgcn_sched_barrier(0);
        __builtin_amdgcn_s_barrier();                // protect buf[tt%3] before re-stage
    }

    // epilogue: 2-pass LDS transpose -> compact upper-triangle f4 stores
    float* lds = reinterpret_cast<float*>(&buf[0][0]);
    const float4* lds4 = reinterpret_cast<const float4*>(lds);
    float4* Sb4 = reinterpret_cast<float4*>(Sbufs) + (size_t)blockIdx.x * S_COMPACT_F4;
#pragma unroll
    for (int jr = 0; jr < 2; ++jr) {
#pragma unroll
        for (int kt = 0; kt < 8; ++kt)
#pragma unroll
            for (int q = 0; q < 4; ++q)
                lds[(w * 16 + 4 * c + q) * 128 + 16 * kt + r] = acc[jr][kt][q];
        __syncthreads();
#pragma unroll
        for (int gi = 0; gi < 4; ++gi) {
            const int g = 2 * gi + jr;
            const int len = 32 - 4 * g;
            const int cnt = 16 * len;
            for (int s = t; s < cnt; s += 256) {
                const int u = s / len;
                const int cf = s - u * len;
                Sb4[OFF_G[g] + s] = lds4[(gi * 16 + u) * 32 + 4 * g + cf];
            }
        }
        __syncthreads();
    }
}

// ---------------- tree-reduce 1024 compact partials -> Sfinal ----------------
__global__ __launch_bounds__(256) void reduce_s(const float4* __restrict__ Sbufs,
                                                float4* __restrict__ Sfinal) {
    __shared__ float4 part[256];
    const int t = threadIdx.x;
    const int slot = blockIdx.x * 16 + (t & 15);     // 144 blocks x 16 = 2304 slots
    const int bg = t >> 4;                           // 16 groups x 64 bufs
    float4 s = (float4){0.f, 0.f, 0.f, 0.f};
#pragma unroll 8
    for (int b = bg * 64; b < bg * 64 + 64; ++b) {
        const float4 u = Sbufs[(size_t)b * S_COMPACT_F4 + slot];
        s.x += u.x; s.y += u.y; s.z += u.z; s.w += u.w;
    }
    part[t] = s;
    __syncthreads();
    for (int off = 128; off >= 16; off >>= 1) {
        if (t < off) {
            float4 a = part[t], b2 = part[t + off];
            a.x += b2.x; a.y += b2.y; a.z += b2.z; a.w += b2.w;
            part[t] = a;
        }
        __syncthreads();
    }
    if (t < 16) {
        int g = 0;
#pragma unroll
        for (int h = 1; h < 8; ++h) if (slot >= OFF_G[h]) g = h;
        int u = 0, cf = 0;
#pragma unroll
        for (int h = 0; h < 8; ++h)
            if (g == h) {
                const int rem = slot - OFF_G[h];
                u = rem / (32 - 4 * h);
                cf = rem - u * (32 - 4 * h);
            }
        Sfinal[(16 * g + u) * 32 + 4 * g + cf] = part[t];
    }
}

// ---------------- make_w: perturbative W = R^{-1}, 4 blocks x 16 columns each ----------------
__global__ __launch_bounds__(256) void make_w(const float* __restrict__ S,
                                              unsigned int* __restrict__ W2h,
                                              unsigned int* __restrict__ W2l) {
    __shared__ float2 A1s[64 * 64];
    __shared__ float2 Wc[64 * 16];
    __shared__ float dinv[64];
    const int t = threadIdx.x;
    const int cb = blockIdx.x * 16;

    if (t < 64)
        dinv[t] = rsqrtf(fmaxf(S[(2 * t) * 128 + 2 * t] + S[(2 * t + 1) * 128 + 2 * t + 1],
                               1e-30f));
    __syncthreads();

    for (int e = t; e < 4096; e += 256) {
        const int j = e >> 6, k = e & 63;
        float2 v = make_float2(0.f, 0.f);
        if (j < k) {
            const float s00 = S[(2 * j) * 128 + 2 * k];
            const float s01 = S[(2 * j) * 128 + 2 * k + 1];
            const float s10 = S[(2 * j + 1) * 128 + 2 * k];
            const float s11 = S[(2 * j + 1) * 128 + 2 * k + 1];
            const float sc = dinv[j] * dinv[k];
            v = make_float2((s00 + s11) * sc, (s01 - s10) * sc);
        }
        A1s[e] = v;
    }
    __syncthreads();

    const int c = cb + (t & 15);
    const int j0 = (t >> 4) * 4;
    float2 m1[4], sq[4];
#pragma unroll
    for (int q = 0; q < 4; ++q) { m1[q] = make_float2(0.f, 0.f); sq[q] = make_float2(0.f, 0.f); }
    for (int m = 0; m < 64; ++m) {
        const float2 amc = A1s[m * 64 + c];
#pragma unroll
        for (int q = 0; q < 4; ++q) {
            const int j = j0 + q;
            const float2 amj = A1s[m * 64 + j];
            const float2 ajm = A1s[j * 64 + m];
            m1[q].x = fmaf(amj.x, amc.x, fmaf(amj.y, amc.y, m1[q].x));
            m1[q].y = fmaf(amj.x, amc.y, fmaf(-amj.y, amc.x, m1[q].y));
            sq[q].x = fmaf(ajm.x, amc.x, fmaf(-ajm.y, amc.y, sq[q].x));
            sq[q].y = fmaf(ajm.x, amc.y, fmaf( ajm.y, amc.x, sq[q].y));
        }
    }

#pragma unroll
    for (int q = 0; q < 4; ++q) {
        const int j = j0 + q;
        float2 v;
        if (j < c) {
            const float2 a = A1s[j * 64 + c];
            v = make_float2(-a.x + m1[q].x + sq[q].x, -a.y + m1[q].y + sq[q].y);
        } else if (j == c) {
            v = make_float2(1.f + 0.5f * m1[q].x, 0.f);
        } else {
            v = make_float2(0.f, 0.f);
        }
        const float dj = dinv[j];
        Wc[j * 16 + (t & 15)] = make_float2(v.x * dj, v.y * dj);
    }
    __syncthreads();

    for (int e = t; e < 2048; e += 256) {
        const int row = 2 * cb + (e >> 6);
        const int j = e & 63;
        const int k = row >> 1;
        const float2 v = (j <= k) ? Wc[j * 16 + (k - cb)] : make_float2(0.f, 0.f);
        float lo, hi;
        if (row & 1) { lo = v.y; hi = v.x; }
        else         { lo = v.x; hi = -v.y; }
        const unsigned short lo_h = f2bf(lo);
        const unsigned short lo_l = f2bf(lo - bf2f(lo_h));
        const unsigned short hi_h = f2bf(hi);
        const unsigned short hi_l = f2bf(hi - bf2f(hi_h));
        W2h[row * 64 + j] = (unsigned int)lo_h | ((unsigned int)hi_h << 16);
        W2l[row * 64 + j] = (unsigned int)lo_l | ((unsigned int)hi_l << 16);
    }
}

// ---------------- Q = Xh * W2t: depth-3 staging, ONE barrier/tile, direct stores ----------------
// Apply A/B history: scattered-store(R19)=scr+nt(R22)=Xh(R23)=~50us -> not VALU/store-format
// bound. This version removes the scr LDS round-trip (-64B/thread LDS), drops to 1
// barrier/tile (stage issued AFTER the barrier; buf[(tt+2)%3] readers provably done
// via store->barrier data-dep), and deepens the pipeline to 3.
#define AP_BLOCKS 2048
#define AP_RTILES 8   // 16 rows per tile

__device__ __forceinline__ void stage_bf(const u32x4* __restrict__ src4,
                                         u32x4* lds0, int t) {
    const int f = t;
    const int sf = f ^ ((f >> 4) & 7);
    const int base = __builtin_amdgcn_readfirstlane(f & ~63);
    __builtin_amdgcn_global_load_lds(
        (const __attribute__((address_space(1))) unsigned int*)(src4 + sf),
        (__attribute__((address_space(3))) unsigned int*)(lds0 + base), 16, 0, 0);
}

__global__ __launch_bounds__(256) void apply_mfma(const u32x4* __restrict__ Xh,
                                                  const unsigned short* __restrict__ W2h,
                                                  const unsigned short* __restrict__ W2l,
                                                  float* __restrict__ Q) {
    __shared__ u32x4 buf[3][256];                // 3 x 4 KB staging
    const int t = threadIdx.x;
    const int w = t >> 6, l = t & 63, r = l & 15, c = l >> 4;

    bf16x8 bh[2][4], bl[2][4];
#pragma unroll
    for (int ct = 0; ct < 2; ++ct)
#pragma unroll
        for (int kc = 0; kc < 4; ++kc) {
            const int idx = (32 * w + 16 * ct + r) * 128 + kc * 32 + c * 8;
            bh[ct][kc] = *reinterpret_cast<const bf16x8*>(W2h + idx);
            bl[ct][kc] = *reinterpret_cast<const bf16x8*>(W2l + idx);
        }
    __builtin_amdgcn_sched_barrier(0);           // pin B-loads before stages (vmcnt order)

    const size_t m0 = (size_t)blockIdx.x * (AP_RTILES * 16);
    const u32x4* Xt = Xh + m0 * 16;              // 16 f4 per row (bf16)
    float* qp = Q + (m0 + 4 * c) * 128 + 32 * w + r;

    stage_bf(Xt, &buf[0][0], t);                 // prologue: tiles 0,1
    stage_bf(Xt + 256, &buf[1][0], t);

    // vmcnt (1 stage + 2 stores per tile; stage issued AFTER barrier):
    // tt=0: stage(1) -> 1 | tt=1: stage(2)+stores(0) -> 3
    // steady: stores(tt-2)+stage(tt+1)+stores(tt-1) -> 5 | tt=NT-1: -> 4
#pragma unroll
    for (int tt = 0; tt < AP_RTILES; ++tt) {
        if (tt == 0)                     { asm volatile("s_waitcnt vmcnt(1)" ::: "memory"); }
        else if (tt == 1)                { asm volatile("s_waitcnt vmcnt(3)" ::: "memory"); }
        else if (tt == AP_RTILES - 1)    { asm volatile("s_waitcnt vmcnt(4)" ::: "memory"); }
        else                             { asm volatile("s_waitcnt vmcnt(5)" ::: "memory"); }
        __builtin_amdgcn_sched_barrier(0);
        __builtin_amdgcn_s_barrier();
        __builtin_amdgcn_sched_barrier(0);

        if (tt + 2 < AP_RTILES)                  // stage AFTER barrier: single-barrier safety
            stage_bf(Xt + (size_t)(tt + 2) * 256, &buf[(tt + 2) % 3][0], t);

        const char* bb = (const char*)&buf[tt % 3][0];
        bf16x8 ah[4];
#pragma unroll
        for (int kc = 0; kc < 4; ++kc) {
            const int w0 = kc * 4 + c;
            ah[kc] = *reinterpret_cast<const bf16x8*>(bb + r * 256 + ((w0 ^ (r & 7)) << 4));
        }
        f32x4 acc[2];
        acc[0] = (f32x4){0.f, 0.f, 0.f, 0.f};
        acc[1] = (f32x4){0.f, 0.f, 0.f, 0.f};
#pragma unroll
        for (int kc = 0; kc < 4; ++kc)
#pragma unroll
            for (int ct = 0; ct < 2; ++ct) {
                acc[ct] = __builtin_amdgcn_mfma_f32_16x16x32_bf16(ah[kc], bh[ct][kc], acc[ct], 0, 0, 0);
                acc[ct] = __builtin_amdgcn_mfma_f32_16x16x32_bf16(ah[kc], bl[ct][kc], acc[ct], 0, 0, 0);
            }
        // direct stores (R19-proven addressing): D col = lane&15, row = (lane>>4)*4 + reg
        float* qt = qp + (size_t)tt * 16 * 128;
#pragma unroll
        for (int ct = 0; ct < 2; ++ct)
#pragma unroll
            for (int q = 0; q < 4; ++q)
                qt[q * 128 + ct * 16] = acc[ct][q];
    }
}

extern "C" void kernel_launch(void* const* d_in, const int* in_sizes, int n_in,
                              void* d_out, int out_size, void* d_ws, size_t ws_size,
                              hipStream_t stream) {
    (void)in_sizes; (void)n_in; (void)out_size; (void)ws_size;
    const float* X = reinterpret_cast<const float*>(d_in[0]);
    float* Q = reinterpret_cast<float*>(d_out);

    // ws: Sbufs 1024 x 36 KB = 36 MB | Xh 64 MB | Sfinal 64 KB | W2h 32 KB | W2l 32 KB
    float* Sbufs = reinterpret_cast<float*>(d_ws);
    char* p = (char*)d_ws + (size_t)GR_BLOCKS * (S_COMPACT_F4 * 16);
    u32x4* Xh = reinterpret_cast<u32x4*>(p);
    p += (size_t)M_ROWS * 256;                   // 128 bf16 per row = 256 B
    float* Sfinal = reinterpret_cast<float*>(p);
    unsigned int* W2h = reinterpret_cast<unsigned int*>(p + 65536);
    unsigned int* W2l = reinterpret_cast<unsigned int*>(p + 65536 + 32768);

    gram_mfma<<<GR_BLOCKS, 256, 0, stream>>>(X, Sbufs, Xh);
    reduce_s<<<144, 256, 0, stream>>>(reinterpret_cast<const float4*>(Sbufs),
                                      reinterpret_cast<float4*>(Sfinal));
    make_w<<<4, 256, 0, stream>>>(Sfinal, W2h, W2l);
    apply_mfma<<<AP_BLOCKS, 256, 0, stream>>>(Xh, reinterpret_cast<const unsigned short*>(W2h),
                                              reinterpret_cast<const unsigned short*>(W2l), Q);
}

// Round 26
// 105.485 us; speedup vs baseline: 1.0898x; 1.0898x over previous
//
#include <hip/hip_runtime.h>
#include <math.h>

#define NCOL 64
#define M_ROWS 262144

typedef short bf16x8 __attribute__((ext_vector_type(8)));
typedef float f32x4 __attribute__((ext_vector_type(4)));
typedef unsigned int u32x4 __attribute__((ext_vector_type(4)));

// compact upper-triangle S storage: tile-row g keeps cols >= 16g.
__device__ __constant__ const int OFF_G[8] = {0, 512, 960, 1344, 1664, 1920, 2112, 2240};
#define S_COMPACT_F4 2304

__device__ __forceinline__ unsigned short f2bf(float f) {  // RNE fp32->bf16
    unsigned int u = __float_as_uint(f);
    u += 0x7FFFu + ((u >> 16) & 1u);
    return (unsigned short)(u >> 16);
}
__device__ __forceinline__ float bf2f(unsigned short s) {
    return __uint_as_float(((unsigned int)s) << 16);
}
__device__ __forceinline__ unsigned int bfrnd(float f) {
    unsigned int u = __float_as_uint(f);
    return u + 0x7FFFu + ((u >> 16) & 1u);
}
__device__ __forceinline__ unsigned int perm_hi16(unsigned int lo, unsigned int hi) {
    return __builtin_amdgcn_perm(hi, lo, 0x07060302u);
}
__device__ __forceinline__ bf16x8 as_bf16x8(u32x4 v) { return __builtin_bit_cast(bf16x8, v); }

// ---------------- S = Y^T Y via MFMA (512 blocks, R23 config); also emits Xh ----------------
#define GR_BLOCKS 512
#define GR_KTILES (M_ROWS / 32 / GR_BLOCKS)  // 16

__device__ __forceinline__ void stage_gram(const float4* __restrict__ src4,
                                           float4* lds0, int t) {
#pragma unroll
    for (int i = 0; i < 4; ++i) {
        const int f = t + 256 * i;
        const int sf = f ^ (((f >> 8) & 1) << 2);
        const int base = __builtin_amdgcn_readfirstlane(f & ~63);
        __builtin_amdgcn_global_load_lds(
            (const __attribute__((address_space(1))) unsigned int*)(src4 + sf),
            (__attribute__((address_space(3))) unsigned int*)(lds0 + base), 16, 0, 0);
    }
}

__global__ __launch_bounds__(256) void gram_mfma(const float* __restrict__ X,
                                                 float* __restrict__ Sbufs,
                                                 u32x4* __restrict__ XhOut) {
    __shared__ float4 buf[3][1024];                  // 3 x 16 KB
    const int t = threadIdx.x;
    const int w = t >> 6, l = t & 63, r = l & 15, c = l >> 4;

    f32x4 acc[2][8];
#pragma unroll
    for (int jr = 0; jr < 2; ++jr)
#pragma unroll
        for (int kt = 0; kt < 8; ++kt) acc[jr][kt] = (f32x4){0.f, 0.f, 0.f, 0.f};

    const float4* Xt4 = reinterpret_cast<const float4*>(X) + (size_t)blockIdx.x * 512 * 32;
    const int rb = c * 4096 + r * 4;
    const int cx = (c & 1);

    stage_gram(Xt4, &buf[0][0], t);                  // prologue: tiles 0,1
    stage_gram(Xt4 + 1024, &buf[1][0], t);

    for (int tt = 0; tt < GR_KTILES; ++tt) {
        if (tt + 2 < GR_KTILES)
            stage_gram(Xt4 + (size_t)(tt + 2) * 1024, &buf[(tt + 2) % 3][0], t);
        // queue accounting (4 stage + 2 xh stores per tile):
        if (tt == 0)                     { asm volatile("s_waitcnt vmcnt(8)" ::: "memory"); }
        else if (tt == 1)                { asm volatile("s_waitcnt vmcnt(10)" ::: "memory"); }
        else if (tt == GR_KTILES - 2)    { asm volatile("s_waitcnt vmcnt(8)" ::: "memory"); }
        else if (tt == GR_KTILES - 1)    { asm volatile("s_waitcnt vmcnt(4)" ::: "memory"); }
        else                             { asm volatile("s_waitcnt vmcnt(12)" ::: "memory"); }
        __builtin_amdgcn_sched_barrier(0);
        __builtin_amdgcn_s_barrier();
        __builtin_amdgcn_sched_barrier(0);

        const char* bb = (const char*)&buf[tt % 3][0];

        // linear bf16 convert + store (coalesced)
        {
            u32x4 xo[2];
#pragma unroll
            for (int i = 0; i < 2; ++i) {
                const int s = t + 256 * i;
                const int row = s >> 4, wv = s & 15;
                const int g0 = row * 32 + wv * 2;
                const int g1 = g0 + 1;
                const int l0 = g0 ^ (((g0 >> 8) & 1) << 2);
                const int l1 = g1 ^ (((g1 >> 8) & 1) << 2);
                const float4 a = *reinterpret_cast<const float4*>(bb + l0 * 16);
                const float4 b2 = *reinterpret_cast<const float4*>(bb + l1 * 16);
                u32x4 o;
                o[0] = perm_hi16(bfrnd(a.x), bfrnd(a.y));
                o[1] = perm_hi16(bfrnd(a.z), bfrnd(a.w));
                o[2] = perm_hi16(bfrnd(b2.x), bfrnd(b2.y));
                o[3] = perm_hi16(bfrnd(b2.z), bfrnd(b2.w));
                xo[i] = o;
            }
            u32x4* Xh4 = XhOut + (size_t)blockIdx.x * (GR_KTILES * 512) + (size_t)tt * 512;
            Xh4[t] = xo[0];
            Xh4[t + 256] = xo[1];
        }

        bf16x8 frag[8];
#pragma unroll
        for (int kt = 0; kt < 8; ++kt) {
            const int cb = (kt ^ cx) * 64;
            float x[8];
#pragma unroll
            for (int i = 0; i < 8; ++i)
                x[i] = *(const float*)(bb + rb + i * 512 + cb);
            u32x4 pw;
#pragma unroll
            for (int wd = 0; wd < 4; ++wd)
                pw[wd] = perm_hi16(bfrnd(x[2 * wd]), bfrnd(x[2 * wd + 1]));
            frag[kt] = as_bf16x8(pw);
        }
#pragma unroll
        for (int s = 0; s < 8; ++s) {
            if ((s >> 1) == w) {
#pragma unroll
                for (int kt = 0; kt < 8; ++kt)
                    acc[s & 1][kt] = __builtin_amdgcn_mfma_f32_16x16x32_bf16(
                        frag[s], frag[kt], acc[s & 1][kt], 0, 0, 0);
            }
        }
        __builtin_amdgcn_sched_barrier(0);
        __builtin_amdgcn_s_barrier();                // protect buf[tt%3] before re-stage
    }

    // epilogue: 2-pass LDS transpose -> compact upper-triangle f4 stores
    float* lds = reinterpret_cast<float*>(&buf[0][0]);
    const float4* lds4 = reinterpret_cast<const float4*>(lds);
    float4* Sb4 = reinterpret_cast<float4*>(Sbufs) + (size_t)blockIdx.x * S_COMPACT_F4;
#pragma unroll
    for (int jr = 0; jr < 2; ++jr) {
#pragma unroll
        for (int kt = 0; kt < 8; ++kt)
#pragma unroll
            for (int q = 0; q < 4; ++q)
                lds[(w * 16 + 4 * c + q) * 128 + 16 * kt + r] = acc[jr][kt][q];
        __syncthreads();
#pragma unroll
        for (int gi = 0; gi < 4; ++gi) {
            const int g = 2 * gi + jr;
            const int len = 32 - 4 * g;
            const int cnt = 16 * len;
            for (int s = t; s < cnt; s += 256) {
                const int u = s / len;
                const int cf = s - u * len;
                Sb4[OFF_G[g] + s] = lds4[(gi * 16 + u) * 32 + 4 * g + cf];
            }
        }
        __syncthreads();
    }
}

// ---------------- tree-reduce 512 compact partials -> Sfinal ----------------
__global__ __launch_bounds__(256) void reduce_s(const float4* __restrict__ Sbufs,
                                                float4* __restrict__ Sfinal) {
    __shared__ float4 part[256];
    const int t = threadIdx.x;
    const int slot = blockIdx.x * 16 + (t & 15);     // 144 blocks x 16 = 2304 slots
    const int bg = t >> 4;                           // 16 groups x 32 bufs
    float4 s = (float4){0.f, 0.f, 0.f, 0.f};
#pragma unroll 8
    for (int b = bg * 32; b < bg * 32 + 32; ++b) {
        const float4 u = Sbufs[(size_t)b * S_COMPACT_F4 + slot];
        s.x += u.x; s.y += u.y; s.z += u.z; s.w += u.w;
    }
    part[t] = s;
    __syncthreads();
    for (int off = 128; off >= 16; off >>= 1) {
        if (t < off) {
            float4 a = part[t], b2 = part[t + off];
            a.x += b2.x; a.y += b2.y; a.z += b2.z; a.w += b2.w;
            part[t] = a;
        }
        __syncthreads();
    }
    if (t < 16) {
        int g = 0;
#pragma unroll
        for (int h = 1; h < 8; ++h) if (slot >= OFF_G[h]) g = h;
        int u = 0, cf = 0;
#pragma unroll
        for (int h = 0; h < 8; ++h)
            if (g == h) {
                const int rem = slot - OFF_G[h];
                u = rem / (32 - 4 * h);
                cf = rem - u * (32 - 4 * h);
            }
        Sfinal[(16 * g + u) * 32 + 4 * g + cf] = part[t];
    }
}

// ---------------- make_w: perturbative W = R^{-1}, 4 blocks x 16 columns each ----------------
__global__ __launch_bounds__(256) void make_w(const float* __restrict__ S,
                                              unsigned int* __restrict__ W2h,
                                              unsigned int* __restrict__ W2l) {
    __shared__ float2 A1s[64 * 64];
    __shared__ float2 Wc[64 * 16];
    __shared__ float dinv[64];
    const int t = threadIdx.x;
    const int cb = blockIdx.x * 16;

    if (t < 64)
        dinv[t] = rsqrtf(fmaxf(S[(2 * t) * 128 + 2 * t] + S[(2 * t + 1) * 128 + 2 * t + 1],
                               1e-30f));
    __syncthreads();

    for (int e = t; e < 4096; e += 256) {
        const int j = e >> 6, k = e & 63;
        float2 v = make_float2(0.f, 0.f);
        if (j < k) {
            const float s00 = S[(2 * j) * 128 + 2 * k];
            const float s01 = S[(2 * j) * 128 + 2 * k + 1];
            const float s10 = S[(2 * j + 1) * 128 + 2 * k];
            const float s11 = S[(2 * j + 1) * 128 + 2 * k + 1];
            const float sc = dinv[j] * dinv[k];
            v = make_float2((s00 + s11) * sc, (s01 - s10) * sc);
        }
        A1s[e] = v;
    }
    __syncthreads();

    const int c = cb + (t & 15);
    const int j0 = (t >> 4) * 4;
    float2 m1[4], sq[4];
#pragma unroll
    for (int q = 0; q < 4; ++q) { m1[q] = make_float2(0.f, 0.f); sq[q] = make_float2(0.f, 0.f); }
    for (int m = 0; m < 64; ++m) {
        const float2 amc = A1s[m * 64 + c];
#pragma unroll
        for (int q = 0; q < 4; ++q) {
            const int j = j0 + q;
            const float2 amj = A1s[m * 64 + j];
            const float2 ajm = A1s[j * 64 + m];
            m1[q].x = fmaf(amj.x, amc.x, fmaf(amj.y, amc.y, m1[q].x));
            m1[q].y = fmaf(amj.x, amc.y, fmaf(-amj.y, amc.x, m1[q].y));
            sq[q].x = fmaf(ajm.x, amc.x, fmaf(-ajm.y, amc.y, sq[q].x));
            sq[q].y = fmaf(ajm.x, amc.y, fmaf( ajm.y, amc.x, sq[q].y));
        }
    }

#pragma unroll
    for (int q = 0; q < 4; ++q) {
        const int j = j0 + q;
        float2 v;
        if (j < c) {
            const float2 a = A1s[j * 64 + c];
            v = make_float2(-a.x + m1[q].x + sq[q].x, -a.y + m1[q].y + sq[q].y);
        } else if (j == c) {
            v = make_float2(1.f + 0.5f * m1[q].x, 0.f);
        } else {
            v = make_float2(0.f, 0.f);
        }
        const float dj = dinv[j];
        Wc[j * 16 + (t & 15)] = make_float2(v.x * dj, v.y * dj);
    }
    __syncthreads();

    for (int e = t; e < 2048; e += 256) {
        const int row = 2 * cb + (e >> 6);
        const int j = e & 63;
        const int k = row >> 1;
        const float2 v = (j <= k) ? Wc[j * 16 + (k - cb)] : make_float2(0.f, 0.f);
        float lo, hi;
        if (row & 1) { lo = v.y; hi = v.x; }
        else         { lo = v.x; hi = -v.y; }
        const unsigned short lo_h = f2bf(lo);
        const unsigned short lo_l = f2bf(lo - bf2f(lo_h));
        const unsigned short hi_h = f2bf(hi);
        const unsigned short hi_l = f2bf(hi - bf2f(hi_h));
        W2h[row * 64 + j] = (unsigned int)lo_h | ((unsigned int)hi_h << 16);
        W2l[row * 64 + j] = (unsigned int)lo_l | ((unsigned int)hi_l << 16);
    }
}

// ---------------- Q = Xh * W2t: depth-3, ONE barrier/tile, direct stores (R25 apply) ----------------
#define AP_BLOCKS 2048
#define AP_RTILES 8   // 16 rows per tile

__device__ __forceinline__ void stage_bf(const u32x4* __restrict__ src4,
                                         u32x4* lds0, int t) {
    const int f = t;
    const int sf = f ^ ((f >> 4) & 7);
    const int base = __builtin_amdgcn_readfirstlane(f & ~63);
    __builtin_amdgcn_global_load_lds(
        (const __attribute__((address_space(1))) unsigned int*)(src4 + sf),
        (__attribute__((address_space(3))) unsigned int*)(lds0 + base), 16, 0, 0);
}

__global__ __launch_bounds__(256) void apply_mfma(const u32x4* __restrict__ Xh,
                                                  const unsigned short* __restrict__ W2h,
                                                  const unsigned short* __restrict__ W2l,
                                                  float* __restrict__ Q) {
    __shared__ u32x4 buf[3][256];                // 3 x 4 KB staging
    const int t = threadIdx.x;
    const int w = t >> 6, l = t & 63, r = l & 15, c = l >> 4;

    bf16x8 bh[2][4], bl[2][4];
#pragma unroll
    for (int ct = 0; ct < 2; ++ct)
#pragma unroll
        for (int kc = 0; kc < 4; ++kc) {
            const int idx = (32 * w + 16 * ct + r) * 128 + kc * 32 + c * 8;
            bh[ct][kc] = *reinterpret_cast<const bf16x8*>(W2h + idx);
            bl[ct][kc] = *reinterpret_cast<const bf16x8*>(W2l + idx);
        }
    __builtin_amdgcn_sched_barrier(0);           // pin B-loads before stages (vmcnt order)

    const size_t m0 = (size_t)blockIdx.x * (AP_RTILES * 16);
    const u32x4* Xt = Xh + m0 * 16;              // 16 f4 per row (bf16)
    float* qp = Q + (m0 + 4 * c) * 128 + 32 * w + r;

    stage_bf(Xt, &buf[0][0], t);                 // prologue: tiles 0,1
    stage_bf(Xt + 256, &buf[1][0], t);

    // vmcnt (1 stage + 2 stores per tile; stage issued AFTER barrier):
    // tt=0: stage(1) -> 1 | tt=1: stage(2)+stores(0) -> 3
    // steady: stores(tt-2)+stage(tt+1)+stores(tt-1) -> 5 | tt=NT-1: -> 4
#pragma unroll
    for (int tt = 0; tt < AP_RTILES; ++tt) {
        if (tt == 0)                     { asm volatile("s_waitcnt vmcnt(1)" ::: "memory"); }
        else if (tt == 1)                { asm volatile("s_waitcnt vmcnt(3)" ::: "memory"); }
        else if (tt == AP_RTILES - 1)    { asm volatile("s_waitcnt vmcnt(4)" ::: "memory"); }
        else                             { asm volatile("s_waitcnt vmcnt(5)" ::: "memory"); }
        __builtin_amdgcn_sched_barrier(0);
        __builtin_amdgcn_s_barrier();
        __builtin_amdgcn_sched_barrier(0);

        if (tt + 2 < AP_RTILES)                  // stage AFTER barrier: single-barrier safety
            stage_bf(Xt + (size_t)(tt + 2) * 256, &buf[(tt + 2) % 3][0], t);

        const char* bb = (const char*)&buf[tt % 3][0];
        bf16x8 ah[4];
#pragma unroll
        for (int kc = 0; kc < 4; ++kc) {
            const int w0 = kc * 4 + c;
            ah[kc] = *reinterpret_cast<const bf16x8*>(bb + r * 256 + ((w0 ^ (r & 7)) << 4));
        }
        f32x4 acc[2];
        acc[0] = (f32x4){0.f, 0.f, 0.f, 0.f};
        acc[1] = (f32x4){0.f, 0.f, 0.f, 0.f};
#pragma unroll
        for (int kc = 0; kc < 4; ++kc)
#pragma unroll
            for (int ct = 0; ct < 2; ++ct) {
                acc[ct] = __builtin_amdgcn_mfma_f32_16x16x32_bf16(ah[kc], bh[ct][kc], acc[ct], 0, 0, 0);
                acc[ct] = __builtin_amdgcn_mfma_f32_16x16x32_bf16(ah[kc], bl[ct][kc], acc[ct], 0, 0, 0);
            }
        // direct stores: D col = lane&15, row = (lane>>4)*4 + reg  [m89/m91]
        float* qt = qp + (size_t)tt * 16 * 128;
#pragma unroll
        for (int ct = 0; ct < 2; ++ct)
#pragma unroll
            for (int q = 0; q < 4; ++q)
                qt[q * 128 + ct * 16] = acc[ct][q];
    }
}

extern "C" void kernel_launch(void* const* d_in, const int* in_sizes, int n_in,
                              void* d_out, int out_size, void* d_ws, size_t ws_size,
                              hipStream_t stream) {
    (void)in_sizes; (void)n_in; (void)out_size; (void)ws_size;
    const float* X = reinterpret_cast<const float*>(d_in[0]);
    float* Q = reinterpret_cast<float*>(d_out);

    // ws: Sbufs 512 x 36 KB = 18 MB | Xh 64 MB | Sfinal 64 KB | W2h 32 KB | W2l 32 KB
    float* Sbufs = reinterpret_cast<float*>(d_ws);
    char* p = (char*)d_ws + (size_t)GR_BLOCKS * (S_COMPACT_F4 * 16);
    u32x4* Xh = reinterpret_cast<u32x4*>(p);
    p += (size_t)M_ROWS * 256;                   // 128 bf16 per row = 256 B
    float* Sfinal = reinterpret_cast<float*>(p);
    unsigned int* W2h = reinterpret_cast<unsigned int*>(p + 65536);
    unsigned int* W2l = reinterpret_cast<unsigned int*>(p + 65536 + 32768);

    gram_mfma<<<GR_BLOCKS, 256, 0, stream>>>(X, Sbufs, Xh);
    reduce_s<<<144, 256, 0, stream>>>(reinterpret_cast<const float4*>(Sbufs),
                                      reinterpret_cast<float4*>(Sfinal));
    make_w<<<4, 256, 0, stream>>>(Sfinal, W2h, W2l);
    apply_mfma<<<AP_BLOCKS, 256, 0, stream>>>(Xh, reinterpret_cast<const unsigned short*>(W2h),
                                              reinterpret_cast<const unsigned short*>(W2l), Q);
}

// Round 27
// 94.409 us; speedup vs baseline: 1.2177x; 1.1173x over previous
//
#include <hip/hip_runtime.h>
#include <math.h>

#define NCOL 64
#define M_ROWS 262144

typedef short bf16x8 __attribute__((ext_vector_type(8)));
typedef float f32x4 __attribute__((ext_vector_type(4)));
typedef unsigned int u32x4 __attribute__((ext_vector_type(4)));

// compact upper-triangle S storage: tile-row g keeps cols >= 16g.
__device__ __constant__ const int OFF_G[8] = {0, 512, 960, 1344, 1664, 1920, 2112, 2240};
#define S_COMPACT_F4 2304

__device__ __forceinline__ unsigned short f2bf(float f) {  // RNE fp32->bf16
    unsigned int u = __float_as_uint(f);
    u += 0x7FFFu + ((u >> 16) & 1u);
    return (unsigned short)(u >> 16);
}
__device__ __forceinline__ float bf2f(unsigned short s) {
    return __uint_as_float(((unsigned int)s) << 16);
}
__device__ __forceinline__ unsigned int bfrnd(float f) {
    unsigned int u = __float_as_uint(f);
    return u + 0x7FFFu + ((u >> 16) & 1u);
}
__device__ __forceinline__ unsigned int perm_hi16(unsigned int lo, unsigned int hi) {
    return __builtin_amdgcn_perm(hi, lo, 0x07060302u);
}
__device__ __forceinline__ bf16x8 as_bf16x8(u32x4 v) { return __builtin_bit_cast(bf16x8, v); }

// ---------------- S = Y^T Y via MFMA (512 blocks); also emits Xh = bf16(X) ----------------
#define GR_BLOCKS 512
#define GR_KTILES (M_ROWS / 32 / GR_BLOCKS)  // 16

__device__ __forceinline__ void stage_gram(const float4* __restrict__ src4,
                                           float4* lds0, int t) {
#pragma unroll
    for (int i = 0; i < 4; ++i) {
        const int f = t + 256 * i;
        const int sf = f ^ (((f >> 8) & 1) << 2);
        const int base = __builtin_amdgcn_readfirstlane(f & ~63);
        __builtin_amdgcn_global_load_lds(
            (const __attribute__((address_space(1))) unsigned int*)(src4 + sf),
            (__attribute__((address_space(3))) unsigned int*)(lds0 + base), 16, 0, 0);
    }
}

__global__ __launch_bounds__(256) void gram_mfma(const float* __restrict__ X,
                                                 float* __restrict__ Sbufs,
                                                 u32x4* __restrict__ XhOut) {
    __shared__ float4 buf[3][1024];                  // 3 x 16 KB
    const int t = threadIdx.x;
    const int w = t >> 6, l = t & 63, r = l & 15, c = l >> 4;

    f32x4 acc[2][8];
#pragma unroll
    for (int jr = 0; jr < 2; ++jr)
#pragma unroll
        for (int kt = 0; kt < 8; ++kt) acc[jr][kt] = (f32x4){0.f, 0.f, 0.f, 0.f};

    const float4* Xt4 = reinterpret_cast<const float4*>(X) + (size_t)blockIdx.x * 512 * 32;
    const int rb = c * 4096 + r * 4;
    const int cx = (c & 1);

    stage_gram(Xt4, &buf[0][0], t);                  // prologue: tiles 0,1
    stage_gram(Xt4 + 1024, &buf[1][0], t);

    for (int tt = 0; tt < GR_KTILES; ++tt) {
        if (tt + 2 < GR_KTILES)
            stage_gram(Xt4 + (size_t)(tt + 2) * 1024, &buf[(tt + 2) % 3][0], t);
        // queue accounting (4 stage + 2 xh stores per tile):
        if (tt == 0)                     { asm volatile("s_waitcnt vmcnt(8)" ::: "memory"); }
        else if (tt == 1)                { asm volatile("s_waitcnt vmcnt(10)" ::: "memory"); }
        else if (tt == GR_KTILES - 2)    { asm volatile("s_waitcnt vmcnt(8)" ::: "memory"); }
        else if (tt == GR_KTILES - 1)    { asm volatile("s_waitcnt vmcnt(4)" ::: "memory"); }
        else                             { asm volatile("s_waitcnt vmcnt(12)" ::: "memory"); }
        __builtin_amdgcn_sched_barrier(0);
        __builtin_amdgcn_s_barrier();
        __builtin_amdgcn_sched_barrier(0);

        const char* bb = (const char*)&buf[tt % 3][0];

        // linear bf16 convert + store (coalesced)
        {
            u32x4 xo[2];
#pragma unroll
            for (int i = 0; i < 2; ++i) {
                const int s = t + 256 * i;
                const int row = s >> 4, wv = s & 15;
                const int g0 = row * 32 + wv * 2;
                const int g1 = g0 + 1;
                const int l0 = g0 ^ (((g0 >> 8) & 1) << 2);
                const int l1 = g1 ^ (((g1 >> 8) & 1) << 2);
                const float4 a = *reinterpret_cast<const float4*>(bb + l0 * 16);
                const float4 b2 = *reinterpret_cast<const float4*>(bb + l1 * 16);
                u32x4 o;
                o[0] = perm_hi16(bfrnd(a.x), bfrnd(a.y));
                o[1] = perm_hi16(bfrnd(a.z), bfrnd(a.w));
                o[2] = perm_hi16(bfrnd(b2.x), bfrnd(b2.y));
                o[3] = perm_hi16(bfrnd(b2.z), bfrnd(b2.w));
                xo[i] = o;
            }
            u32x4* Xh4 = XhOut + (size_t)blockIdx.x * (GR_KTILES * 512) + (size_t)tt * 512;
            Xh4[t] = xo[0];
            Xh4[t + 256] = xo[1];
        }

        bf16x8 frag[8];
#pragma unroll
        for (int kt = 0; kt < 8; ++kt) {
            const int cb = (kt ^ cx) * 64;
            float x[8];
#pragma unroll
            for (int i = 0; i < 8; ++i)
                x[i] = *(const float*)(bb + rb + i * 512 + cb);
            u32x4 pw;
#pragma unroll
            for (int wd = 0; wd < 4; ++wd)
                pw[wd] = perm_hi16(bfrnd(x[2 * wd]), bfrnd(x[2 * wd + 1]));
            frag[kt] = as_bf16x8(pw);
        }
#pragma unroll
        for (int s = 0; s < 8; ++s) {
            if ((s >> 1) == w) {
#pragma unroll
                for (int kt = 0; kt < 8; ++kt)
                    acc[s & 1][kt] = __builtin_amdgcn_mfma_f32_16x16x32_bf16(
                        frag[s], frag[kt], acc[s & 1][kt], 0, 0, 0);
            }
        }
        __builtin_amdgcn_sched_barrier(0);
        __builtin_amdgcn_s_barrier();                // protect buf[tt%3] before re-stage
    }

    // epilogue: 2-pass LDS transpose -> compact upper-triangle f4 stores
    float* lds = reinterpret_cast<float*>(&buf[0][0]);
    const float4* lds4 = reinterpret_cast<const float4*>(lds);
    float4* Sb4 = reinterpret_cast<float4*>(Sbufs) + (size_t)blockIdx.x * S_COMPACT_F4;
#pragma unroll
    for (int jr = 0; jr < 2; ++jr) {
#pragma unroll
        for (int kt = 0; kt < 8; ++kt)
#pragma unroll
            for (int q = 0; q < 4; ++q)
                lds[(w * 16 + 4 * c + q) * 128 + 16 * kt + r] = acc[jr][kt][q];
        __syncthreads();
#pragma unroll
        for (int gi = 0; gi < 4; ++gi) {
            const int g = 2 * gi + jr;
            const int len = 32 - 4 * g;
            const int cnt = 16 * len;
            for (int s = t; s < cnt; s += 256) {
                const int u = s / len;
                const int cf = s - u * len;
                Sb4[OFF_G[g] + s] = lds4[(gi * 16 + u) * 32 + 4 * g + cf];
            }
        }
        __syncthreads();
    }
}

// ---------------- tree-reduce 512 compact partials -> Sfinal ----------------
__global__ __launch_bounds__(256) void reduce_s(const float4* __restrict__ Sbufs,
                                                float4* __restrict__ Sfinal) {
    __shared__ float4 part[256];
    const int t = threadIdx.x;
    const int slot = blockIdx.x * 16 + (t & 15);     // 144 blocks x 16 = 2304 slots
    const int bg = t >> 4;                           // 16 groups x 32 bufs
    float4 s = (float4){0.f, 0.f, 0.f, 0.f};
#pragma unroll 8
    for (int b = bg * 32; b < bg * 32 + 32; ++b) {
        const float4 u = Sbufs[(size_t)b * S_COMPACT_F4 + slot];
        s.x += u.x; s.y += u.y; s.z += u.z; s.w += u.w;
    }
    part[t] = s;
    __syncthreads();
    for (int off = 128; off >= 16; off >>= 1) {
        if (t < off) {
            float4 a = part[t], b2 = part[t + off];
            a.x += b2.x; a.y += b2.y; a.z += b2.z; a.w += b2.w;
            part[t] = a;
        }
        __syncthreads();
    }
    if (t < 16) {
        int g = 0;
#pragma unroll
        for (int h = 1; h < 8; ++h) if (slot >= OFF_G[h]) g = h;
        int u = 0, cf = 0;
#pragma unroll
        for (int h = 0; h < 8; ++h)
            if (g == h) {
                const int rem = slot - OFF_G[h];
                u = rem / (32 - 4 * h);
                cf = rem - u * (32 - 4 * h);
            }
        Sfinal[(16 * g + u) * 32 + 4 * g + cf] = part[t];
    }
}

// ---------------- make_w: perturbative W = R^{-1}, 4 blocks x 16 columns each ----------------
__global__ __launch_bounds__(256) void make_w(const float* __restrict__ S,
                                              unsigned int* __restrict__ W2h,
                                              unsigned int* __restrict__ W2l) {
    __shared__ float2 A1s[64 * 64];
    __shared__ float2 Wc[64 * 16];
    __shared__ float dinv[64];
    const int t = threadIdx.x;
    const int cb = blockIdx.x * 16;

    if (t < 64)
        dinv[t] = rsqrtf(fmaxf(S[(2 * t) * 128 + 2 * t] + S[(2 * t + 1) * 128 + 2 * t + 1],
                               1e-30f));
    __syncthreads();

    for (int e = t; e < 4096; e += 256) {
        const int j = e >> 6, k = e & 63;
        float2 v = make_float2(0.f, 0.f);
        if (j < k) {
            const float s00 = S[(2 * j) * 128 + 2 * k];
            const float s01 = S[(2 * j) * 128 + 2 * k + 1];
            const float s10 = S[(2 * j + 1) * 128 + 2 * k];
            const float s11 = S[(2 * j + 1) * 128 + 2 * k + 1];
            const float sc = dinv[j] * dinv[k];
            v = make_float2((s00 + s11) * sc, (s01 - s10) * sc);
        }
        A1s[e] = v;
    }
    __syncthreads();

    const int c = cb + (t & 15);
    const int j0 = (t >> 4) * 4;
    float2 m1[4], sq[4];
#pragma unroll
    for (int q = 0; q < 4; ++q) { m1[q] = make_float2(0.f, 0.f); sq[q] = make_float2(0.f, 0.f); }
    for (int m = 0; m < 64; ++m) {
        const float2 amc = A1s[m * 64 + c];
#pragma unroll
        for (int q = 0; q < 4; ++q) {
            const int j = j0 + q;
            const float2 amj = A1s[m * 64 + j];
            const float2 ajm = A1s[j * 64 + m];
            m1[q].x = fmaf(amj.x, amc.x, fmaf(amj.y, amc.y, m1[q].x));
            m1[q].y = fmaf(amj.x, amc.y, fmaf(-amj.y, amc.x, m1[q].y));
            sq[q].x = fmaf(ajm.x, amc.x, fmaf(-ajm.y, amc.y, sq[q].x));
            sq[q].y = fmaf(ajm.x, amc.y, fmaf( ajm.y, amc.x, sq[q].y));
        }
    }

#pragma unroll
    for (int q = 0; q < 4; ++q) {
        const int j = j0 + q;
        float2 v;
        if (j < c) {
            const float2 a = A1s[j * 64 + c];
            v = make_float2(-a.x + m1[q].x + sq[q].x, -a.y + m1[q].y + sq[q].y);
        } else if (j == c) {
            v = make_float2(1.f + 0.5f * m1[q].x, 0.f);
        } else {
            v = make_float2(0.f, 0.f);
        }
        const float dj = dinv[j];
        Wc[j * 16 + (t & 15)] = make_float2(v.x * dj, v.y * dj);
    }
    __syncthreads();

    for (int e = t; e < 2048; e += 256) {
        const int row = 2 * cb + (e >> 6);
        const int j = e & 63;
        const int k = row >> 1;
        const float2 v = (j <= k) ? Wc[j * 16 + (k - cb)] : make_float2(0.f, 0.f);
        float lo, hi;
        if (row & 1) { lo = v.y; hi = v.x; }
        else         { lo = v.x; hi = -v.y; }
        const unsigned short lo_h = f2bf(lo);
        const unsigned short lo_l = f2bf(lo - bf2f(lo_h));
        const unsigned short hi_h = f2bf(hi);
        const unsigned short hi_l = f2bf(hi - bf2f(hi_h));
        W2h[row * 64 + j] = (unsigned int)lo_h | ((unsigned int)hi_h << 16);
        W2l[row * 64 + j] = (unsigned int)lo_l | ((unsigned int)hi_l << 16);
    }
}

// ---------------- Q = Xh * W2t: depth-3 staging + scr transpose + full-line nt stores ----------------
// R26 lesson: scattered 4B stores cost ~8-10us vs full-line nt (R19 vs R22/R23) -> keep scr.
// R26's sound part kept: depth-3 with stage issued AFTER the top barrier (safe: tile tt-1's
// mid barrier + lgkmcnt(0) retired all ah-reads of buf[(tt+2)%3] before tile tt's top barrier).
#define AP_BLOCKS 2048
#define AP_RTILES 8   // 16 rows per tile

__device__ __forceinline__ void stage_bf(const u32x4* __restrict__ src4,
                                         u32x4* lds0, int t) {
    const int f = t;
    const int sf = f ^ ((f >> 4) & 7);
    const int base = __builtin_amdgcn_readfirstlane(f & ~63);
    __builtin_amdgcn_global_load_lds(
        (const __attribute__((address_space(1))) unsigned int*)(src4 + sf),
        (__attribute__((address_space(3))) unsigned int*)(lds0 + base), 16, 0, 0);
}

__global__ __launch_bounds__(256) void apply_mfma(const u32x4* __restrict__ Xh,
                                                  const unsigned short* __restrict__ W2h,
                                                  const unsigned short* __restrict__ W2l,
                                                  float* __restrict__ Q) {
    __shared__ u32x4 buf[3][256];                // 3 x 4 KB staging
    __shared__ float scr[16 * 132];              // 8.25 KB transpose scratch
    const int t = threadIdx.x;
    const int w = t >> 6, l = t & 63, r = l & 15, c = l >> 4;

    bf16x8 bh[2][4], bl[2][4];
#pragma unroll
    for (int ct = 0; ct < 2; ++ct)
#pragma unroll
        for (int kc = 0; kc < 4; ++kc) {
            const int idx = (32 * w + 16 * ct + r) * 128 + kc * 32 + c * 8;
            bh[ct][kc] = *reinterpret_cast<const bf16x8*>(W2h + idx);
            bl[ct][kc] = *reinterpret_cast<const bf16x8*>(W2l + idx);
        }
    __builtin_amdgcn_sched_barrier(0);           // pin B-loads before stages (vmcnt order)

    const size_t m0 = (size_t)blockIdx.x * (AP_RTILES * 16);
    const u32x4* Xt = Xh + m0 * 16;              // 16 f4 per row (bf16)
    f32x4* Q4 = reinterpret_cast<f32x4*>(Q) + m0 * 32;

    stage_bf(Xt, &buf[0][0], t);                 // prologue: tiles 0,1
    stage_bf(Xt + 256, &buf[1][0], t);

    // vmcnt (1 stage + 2 nt stores per tile; stage issued AFTER top barrier):
    // tt=0: stage(1) -> 1 | tt=1: stage(2)+stores(0) -> 3
    // steady: stores(tt-2)+stage(tt+1)+stores(tt-1) -> 5 | tt=NT-1: -> 4
#pragma unroll
    for (int tt = 0; tt < AP_RTILES; ++tt) {
        if (tt == 0)                     { asm volatile("s_waitcnt vmcnt(1)" ::: "memory"); }
        else if (tt == 1)                { asm volatile("s_waitcnt vmcnt(3)" ::: "memory"); }
        else if (tt == AP_RTILES - 1)    { asm volatile("s_waitcnt vmcnt(4)" ::: "memory"); }
        else                             { asm volatile("s_waitcnt vmcnt(5)" ::: "memory"); }
        __builtin_amdgcn_sched_barrier(0);
        __builtin_amdgcn_s_barrier();
        __builtin_amdgcn_sched_barrier(0);

        if (tt + 2 < AP_RTILES)                  // stage after barrier (R26's sound part)
            stage_bf(Xt + (size_t)(tt + 2) * 256, &buf[(tt + 2) % 3][0], t);

        const char* bb = (const char*)&buf[tt % 3][0];
        bf16x8 ah[4];
#pragma unroll
        for (int kc = 0; kc < 4; ++kc) {
            const int w0 = kc * 4 + c;
            ah[kc] = *reinterpret_cast<const bf16x8*>(bb + r * 256 + ((w0 ^ (r & 7)) << 4));
        }
        f32x4 acc[2];
        acc[0] = (f32x4){0.f, 0.f, 0.f, 0.f};
        acc[1] = (f32x4){0.f, 0.f, 0.f, 0.f};
#pragma unroll
        for (int kc = 0; kc < 4; ++kc)
#pragma unroll
            for (int ct = 0; ct < 2; ++ct) {
                acc[ct] = __builtin_amdgcn_mfma_f32_16x16x32_bf16(ah[kc], bh[ct][kc], acc[ct], 0, 0, 0);
                acc[ct] = __builtin_amdgcn_mfma_f32_16x16x32_bf16(ah[kc], bl[ct][kc], acc[ct], 0, 0, 0);
            }
        // transpose acc through scr: D col = lane&15, row = (lane>>4)*4 + reg [m89/m91]
#pragma unroll
        for (int ct = 0; ct < 2; ++ct)
#pragma unroll
            for (int q = 0; q < 4; ++q)
                scr[(4 * c + q) * 132 + 32 * w + 16 * ct + r] = acc[ct][q];
        asm volatile("s_waitcnt lgkmcnt(0)" ::: "memory");   // drain ds_writes (R21 lesson)
        __builtin_amdgcn_sched_barrier(0);
        __builtin_amdgcn_s_barrier();            // scr visible; ah-reads retired (depth-3 safety)
        __builtin_amdgcn_sched_barrier(0);
        // row-linear readback -> full-line nt f32x4 stores
#pragma unroll
        for (int i = 0; i < 2; ++i) {
            const int slot = t + 256 * i;        // 512 f4 = 16 rows x 32
            const int row = slot >> 5;
            const int cf = slot & 31;
            const f32x4 v = *reinterpret_cast<const f32x4*>(scr + row * 132 + cf * 4);
            __builtin_nontemporal_store(v, Q4 + (size_t)(tt * 16 + row) * 32 + cf);
        }
    }
}

extern "C" void kernel_launch(void* const* d_in, const int* in_sizes, int n_in,
                              void* d_out, int out_size, void* d_ws, size_t ws_size,
                              hipStream_t stream) {
    (void)in_sizes; (void)n_in; (void)out_size; (void)ws_size;
    const float* X = reinterpret_cast<const float*>(d_in[0]);
    float* Q = reinterpret_cast<float*>(d_out);

    // ws: Sbufs 512 x 36 KB = 18 MB | Xh 64 MB | Sfinal 64 KB | W2h 32 KB | W2l 32 KB
    float* Sbufs = reinterpret_cast<float*>(d_ws);
    char* p = (char*)d_ws + (size_t)GR_BLOCKS * (S_COMPACT_F4 * 16);
    u32x4* Xh = reinterpret_cast<u32x4*>(p);
    p += (size_t)M_ROWS * 256;                   // 128 bf16 per row = 256 B
    float* Sfinal = reinterpret_cast<float*>(p);
    unsigned int* W2h = reinterpret_cast<unsigned int*>(p + 65536);
    unsigned int* W2l = reinterpret_cast<unsigned int*>(p + 65536 + 32768);

    gram_mfma<<<GR_BLOCKS, 256, 0, stream>>>(X, Sbufs, Xh);
    reduce_s<<<144, 256, 0, stream>>>(reinterpret_cast<const float4*>(Sbufs),
                                      reinterpret_cast<float4*>(Sfinal));
    make_w<<<4, 256, 0, stream>>>(Sfinal, W2h, W2l);
    apply_mfma<<<AP_BLOCKS, 256, 0, stream>>>(Xh, reinterpret_cast<const unsigned short*>(W2h),
                                              reinterpret_cast<const unsigned short*>(W2l), Q);
}